// Round 6
// baseline (1039.008 us; speedup 1.0000x reference)
//
#include <hip/hip_runtime.h>
#include <hip/hip_bf16.h>
#include <stdint.h>

// ---------- types ----------
typedef __attribute__((ext_vector_type(4))) float  f32x4;
typedef __attribute__((ext_vector_type(8))) short  bf16x8;
typedef __attribute__((ext_vector_type(8))) unsigned short u16x8;

#define MFMA16(d, x, y) d = __builtin_amdgcn_mfma_f32_16x16x32_bf16(x, y, d, 0, 0, 0)

// round f32 -> bf16 bits (RNE)
static __device__ inline unsigned short f2bf(float f) {
    union { float f; unsigned u; } a; a.f = f;
    unsigned u = a.u;
    unsigned lsb = (u >> 16) & 1u;
    u += 0x7fffu + lsb;
    return (unsigned short)(u >> 16);
}

// Emulate reference fp8_e4m3_round for positive x (x >= 1e-12).
static __device__ inline float fp8_e4m3_round(float x) {
    union { float f; unsigned u; } a; a.f = x;
    int e = (int)((a.u >> 23) & 255u) - 127;   // floor(log2(x)) exactly
    e = e < -6 ? -6 : (e > 8 ? 8 : e);
    union { unsigned u; float f; } stp, inv;
    stp.u = (unsigned)(e - 3 + 127) << 23;     // 2^(e-3)
    inv.u = (unsigned)(3 - e + 127) << 23;     // 2^(3-e)
    float r = rintf(x * inv.f) * stp.f;        // round-half-even == jnp.round
    return fminf(r, 448.0f);
}

// fp4 e2m1 level by strict midpoint comparison
static __device__ inline float fp4_level(float a) {
    return a > 2.5f ? (a > 3.5f ? (a > 5.0f ? 6.0f : 4.0f) : 3.0f)
                    : (a > 1.25f ? (a > 1.75f ? 2.0f : 1.5f)
                                 : (a > 0.75f ? 1.0f : (a > 0.25f ? 0.5f : 0.0f)));
}

// ---------- kernel 1: quantize+dequantize activations to bf16 ----------
__global__ void quant_x_kernel(const float* __restrict__ x, unsigned short* __restrict__ xd, int nblk) {
    int i = blockIdx.x * blockDim.x + threadIdx.x;
    if (i >= nblk) return;
    const float4* p = (const float4*)(x + (size_t)i * 16);
    float4 v0 = p[0], v1 = p[1], v2 = p[2], v3 = p[3];
    float vals[16] = { v0.x,v0.y,v0.z,v0.w, v1.x,v1.y,v1.z,v1.w,
                       v2.x,v2.y,v2.z,v2.w, v3.x,v3.y,v3.z,v3.w };
    float amax = 0.0f;
#pragma unroll
    for (int j = 0; j < 16; ++j) amax = fmaxf(amax, fabsf(vals[j]));
    float s0 = fmaxf(amax / 6.0f, 1e-12f);
    float s  = fmaxf(fp8_e4m3_round(s0), 1.0f / 512.0f);  // FP8_MIN = 2^-9
    u16x8 o0, o1;
#pragma unroll
    for (int j = 0; j < 16; ++j) {
        float v = vals[j] / s;
        float lev = fp4_level(fabsf(v));
        float q = copysignf(lev, v);
        unsigned short b = f2bf(q * s);
        if (j < 8) o0[j] = b; else o1[j - 8] = b;
    }
    u16x8* dst = (u16x8*)(xd + (size_t)i * 16);
    dst[0] = o0; dst[1] = o1;
}

// ---------- kernel 2: dequantize weights to bf16 ----------
__global__ void deq_w_kernel(const float* __restrict__ wq, const float* __restrict__ wsc,
                             unsigned short* __restrict__ wd, int nblk) {
    int i = blockIdx.x * blockDim.x + threadIdx.x;
    if (i >= nblk) return;
    float s = wsc[i];
    const float4* p = (const float4*)(wq + (size_t)i * 16);
    float4 v0 = p[0], v1 = p[1], v2 = p[2], v3 = p[3];
    float vals[16] = { v0.x,v0.y,v0.z,v0.w, v1.x,v1.y,v1.z,v1.w,
                       v2.x,v2.y,v2.z,v2.w, v3.x,v3.y,v3.z,v3.w };
    u16x8 o0, o1;
#pragma unroll
    for (int j = 0; j < 16; ++j) {
        unsigned short b = f2bf(vals[j] * s);
        if (j < 8) o0[j] = b; else o1[j - 8] = b;
    }
    u16x8* dst = (u16x8*)(wd + (size_t)i * 16);
    dst[0] = o0; dst[1] = o1;
}

// ---------- kernel 3: 256x256x64 pipelined bf16 GEMM, A via LDS, B via regs --
// C[M][N] = A[M][K] * B[N][K]^T + bias.  8 waves (2Mx4N), per-wave 128x64.
// LDS (64KB): A only, dbuf 32KB tiles, st_16x32-swizzled 1024B subtiles.
// B fragments load global->VGPR (lanes {l,l+16,l+32,l+48} = one 64B segment;
// B panel is L2-hot, 2x redundancy).  LDS traffic/K-tile: 256KB -> 160KB,
// now strictly below the MFMA floor.
// Phases per tile (2 barriers each); ds_reads issued ONE PHASE EARLY under
// MFMA cover:
//  P1: gload B-k1(cur); bar; lgkm0; MFMA a x k0[0,1]; bar
//  P2: stage A(t+2)h0; dsr a2<-k1(cur buf); vmcnt(12); bar; MFMA a x k0[2,3]; bar
//  P3: gload B-k0(next); bar; lgkm0; MFMA a2 x k1[0,1]; bar
//  P4: stage A(t+2)h1; dsr a<-k0(next buf); vmcnt(12); bar; MFMA a2 x k1[2,3]; bar
// WAR: stage at P2/P4 is safe because the dsr of the overwritten region was
// drained by ALL waves at the preceding P1/P3 lgkm(0) (pre-barrier).
// RAW: A(t+2)h0 staged P2(t), first dsr P4(t+1); gate vmcnt(12)@P2-end.
//      A(t+2)h1 staged P4(t), first dsr P2(t+2); gate vmcnt(12)@P4-end.
//      (per-tile vm order: 4B,2A,4B,2A = 12 -> keep newest 12, drain older.)
// B-reg RAW: compiler-tracked counted vmcnt (reg defs visible).
static __device__ __forceinline__ void stage_half(const unsigned short* g0, const unsigned short* g1,
                                                  size_t koff, char* d0) {
    __builtin_amdgcn_global_load_lds((const __attribute__((address_space(1))) void*)(g0 + koff),
                                     (__attribute__((address_space(3))) void*)d0, 16, 0, 0);
    __builtin_amdgcn_global_load_lds((const __attribute__((address_space(1))) void*)(g1 + koff),
                                     (__attribute__((address_space(3))) void*)(d0 + 1024), 16, 0, 0);
}

#define LOADB4(dst, koff) {                                             \
    dst[0] = *(const bf16x8*)(gBr + (size_t)(koff));                    \
    dst[1] = *(const bf16x8*)(gBr + bstride + (size_t)(koff));          \
    dst[2] = *(const bf16x8*)(gBr + 2 * bstride + (size_t)(koff));      \
    dst[3] = *(const bf16x8*)(gBr + 3 * bstride + (size_t)(koff)); }

#define MFMA_HALF(AV, BV, n0) {                                         \
    _Pragma("unroll")                                                   \
    for (int mf = 0; mf < 8; ++mf) {                                    \
        MFMA16(acc[mf][n0], AV[mf], BV[n0]);                            \
        MFMA16(acc[mf][n0 + 1], AV[mf], BV[n0 + 1]);                    \
    } }

#define BODY(T, BUFC, BUFN, K0C, K1C, K0N) {                                      \
    const size_t t64 = (size_t)(T) * 64;                                          \
    /* P1 */                                                                      \
    LOADB4(K1C, t64 + 32);                                                        \
    __builtin_amdgcn_s_barrier();                                                 \
    asm volatile("s_waitcnt lgkmcnt(0)" ::: "memory");                            \
    __builtin_amdgcn_s_setprio(1);                                                \
    MFMA_HALF(a, K0C, 0);                                                         \
    __builtin_amdgcn_s_setprio(0);                                                \
    __builtin_amdgcn_s_barrier();                                                 \
    /* P2 */                                                                      \
    stage_half(gA0, gA1, t64 + 128, ldsA_w + (BUFC) * 32768);                     \
    { const char* pc = lds + (BUFC) * 32768 + wr * 8192 + lane_off + 16384;       \
      _Pragma("unroll")                                                           \
      for (int i = 0; i < 8; ++i) a2[i] = *(const bf16x8*)(pc + i * 1024); }      \
    asm volatile("s_waitcnt vmcnt(12)" ::: "memory");                             \
    __builtin_amdgcn_s_barrier();                                                 \
    __builtin_amdgcn_s_setprio(1);                                                \
    MFMA_HALF(a, K0C, 2);                                                         \
    __builtin_amdgcn_s_setprio(0);                                                \
    __builtin_amdgcn_s_barrier();                                                 \
    /* P3 */                                                                      \
    LOADB4(K0N, t64 + 64);                                                        \
    __builtin_amdgcn_s_barrier();                                                 \
    asm volatile("s_waitcnt lgkmcnt(0)" ::: "memory");                            \
    __builtin_amdgcn_s_setprio(1);                                                \
    MFMA_HALF(a2, K1C, 0);                                                        \
    __builtin_amdgcn_s_setprio(0);                                                \
    __builtin_amdgcn_s_barrier();                                                 \
    /* P4 */                                                                      \
    stage_half(gA0, gA1, t64 + 160, ldsA_w + (BUFC) * 32768 + 16384);             \
    { const char* pn = lds + (BUFN) * 32768 + wr * 8192 + lane_off;               \
      _Pragma("unroll")                                                           \
      for (int i = 0; i < 8; ++i) a[i] = *(const bf16x8*)(pn + i * 1024); }       \
    asm volatile("s_waitcnt vmcnt(12)" ::: "memory");                             \
    __builtin_amdgcn_s_barrier();                                                 \
    __builtin_amdgcn_s_setprio(1);                                                \
    MFMA_HALF(a2, K1C, 2);                                                        \
    __builtin_amdgcn_s_setprio(0);                                                \
    __builtin_amdgcn_s_barrier(); }

__global__ __launch_bounds__(512, 2)
void gemm_kernel(const unsigned short* __restrict__ A, const unsigned short* __restrict__ Bw,
                 const float* __restrict__ bias, float* __restrict__ C,
                 int M, int N, int K) {
    extern __shared__ char lds[];
    const int tid  = threadIdx.x;
    const int lane = tid & 63;
    const int wid  = tid >> 6;
    const int wr   = wid >> 2;       // 0..1
    const int wc   = wid & 3;        // 0..3

    const int NXB = N >> 8, NYB = M >> 8;
    int bid = blockIdx.x;
    int bx, by;
    if (NXB == 64 && NYB == 16) {    // XCD-aware swizzle (8 XCDs, 1024 wgs)
        int xcd = bid & 7, c = bid >> 3;
        bx = xcd * 8 + (c & 7);
        by = c >> 3;
    } else { bx = bid % NXB; by = bid / NXB; }

    const int NT = K >> 6;           // K-tiles of 64

    // read-side swizzled lane offset within a 1024B subtile (st_16x32, 1 bit)
    int w0 = (lane & 15) * 64 + ((lane >> 4) << 4);
    const int lane_off = w0 ^ (((w0 >> 9) & 1) << 5);
    // write-side inverse permutation for A staging: lane -> (row, col)
    const int u   = (lane * 16) ^ (lane & 32);
    const int r_l = u >> 6;
    const int c_l = (u & 63) >> 1;

    const unsigned short* gA0 = A + (size_t)(by * 256 + wid * 32 + r_l) * K + c_l;
    const unsigned short* gA1 = gA0 + (size_t)16 * K;
    char* ldsA_w = lds + wid * 2048 + lane * 16;           // + buf*32768 + s*16384

    // B register-load base: lane reads B[wc*64 + nf*16 + (lane&15)][k + (lane>>4)*8 ..+8]
    const size_t bstride = (size_t)16 * K;                 // 16 rows
    const unsigned short* gBr = Bw + (size_t)(bx * 256 + wc * 64 + (lane & 15)) * K
                                   + ((lane >> 4) << 3);

    f32x4 acc[8][4];
#pragma unroll
    for (int m = 0; m < 8; ++m)
#pragma unroll
        for (int n = 0; n < 4; ++n)
#pragma unroll
            for (int j = 0; j < 4; ++j) acc[m][n][j] = 0.0f;

    bf16x8 a[8], a2[8];
    bf16x8 b0x[4], b1x[4], b0y[4], b1y[4];

    // ---- prologue: stage A(0),A(1); load B-k0(0); first dsr ----
    stage_half(gA0, gA1, 0,   ldsA_w);                 // A0 h0
    stage_half(gA0, gA1, 32,  ldsA_w + 16384);         // A0 h1
    stage_half(gA0, gA1, 64,  ldsA_w + 32768);         // A1 h0
    stage_half(gA0, gA1, 96,  ldsA_w + 32768 + 16384); // A1 h1
    LOADB4(b0x, 0);                                    // k0 of tile0
    asm volatile("s_waitcnt vmcnt(8)" ::: "memory");   // A0's 4 lds-loads landed
    __builtin_amdgcn_s_barrier();
    {
        const char* p0 = lds + wr * 8192 + lane_off;
#pragma unroll
        for (int i = 0; i < 8; ++i) a[i] = *(const bf16x8*)(p0 + i * 1024);
    }

    // ---- main loop: tiles 0..NT-3 in even/odd pairs (B reg ping-pong) ----
    for (int t = 0; t <= NT - 4; t += 2) {
        BODY(t,     0, 1, b0x, b1x, b0y);
        BODY(t + 1, 1, 0, b0y, b1y, b0x);
    }

    // ---- tail: tiles NT-2 (buf0), NT-1 (buf1); a holds A(NT-2)k0, b0x = k0(NT-2)
    LOADB4(b1x, (size_t)(NT - 2) * 64 + 32);   // k1(NT-2)
    LOADB4(b0y, (size_t)(NT - 1) * 64);        // k0(NT-1)
    LOADB4(b1y, (size_t)(NT - 1) * 64 + 32);   // k1(NT-1)
    asm volatile("s_waitcnt vmcnt(0)" ::: "memory");
    __builtin_amdgcn_s_barrier();
    asm volatile("s_waitcnt lgkmcnt(0)" ::: "memory");
    MFMA_HALF(a, b0x, 0); MFMA_HALF(a, b0x, 2);
    {
        const char* pc = lds + wr * 8192 + lane_off + 16384;
#pragma unroll
        for (int i = 0; i < 8; ++i) a2[i] = *(const bf16x8*)(pc + i * 1024);
    }
    MFMA_HALF(a2, b1x, 0); MFMA_HALF(a2, b1x, 2);
    {
        const char* pn = lds + 32768 + wr * 8192 + lane_off;
#pragma unroll
        for (int i = 0; i < 8; ++i) a[i] = *(const bf16x8*)(pn + i * 1024);
    }
    MFMA_HALF(a, b0y, 0); MFMA_HALF(a, b0y, 2);
    {
        const char* pn2 = lds + 32768 + wr * 8192 + lane_off + 16384;
#pragma unroll
        for (int i = 0; i < 8; ++i) a2[i] = *(const bf16x8*)(pn2 + i * 1024);
    }
    MFMA_HALF(a2, b1y, 0); MFMA_HALF(a2, b1y, 2);

    // ---- C write: col = lane&15, row = (lane>>4)*4 + j ----
    const int row0 = by * 256 + wr * 128;
    const int col0 = bx * 256 + wc * 64;
#pragma unroll
    for (int nf = 0; nf < 4; ++nf) {
        int col = col0 + nf * 16 + (lane & 15);
        float bv = bias[col];
#pragma unroll
        for (int mf = 0; mf < 8; ++mf) {
#pragma unroll
            for (int j = 0; j < 4; ++j) {
                int row = row0 + mf * 16 + ((lane >> 4) << 2) + j;
                C[(size_t)row * N + col] = acc[mf][nf][j] + bv;
            }
        }
    }
}

// ---------- host ----------
extern "C" void kernel_launch(void* const* d_in, const int* in_sizes, int n_in,
                              void* d_out, int out_size, void* d_ws, size_t ws_size,
                              hipStream_t stream) {
    const float* x    = (const float*)d_in[0];
    const float* wq   = (const float*)d_in[1];
    const float* wsc  = (const float*)d_in[2];
    const float* bias = (const float*)d_in[3];
    float* out = (float*)d_out;

    const long N = in_sizes[3];                 // 16384
    const long K = (long)in_sizes[1] / N;       // 4096
    const long M = (long)in_sizes[0] / K;       // 4096

    size_t need = ((size_t)(M * K) + (size_t)(N * K)) * sizeof(unsigned short);
    if (ws_size < need) return;

    unsigned short* xd = (unsigned short*)d_ws;          // [M][K] bf16
    unsigned short* wd = xd + (size_t)M * K;             // [N][K] bf16

    {
        int nblk = (int)(M * K / 16);
        quant_x_kernel<<<(nblk + 255) / 256, 256, 0, stream>>>(x, xd, nblk);
    }
    {
        int nblk = (int)(N * K / 16);
        deq_w_kernel<<<(nblk + 255) / 256, 256, 0, stream>>>(wq, wsc, wd, nblk);
    }
    {
        hipFuncSetAttribute((const void*)gemm_kernel,
                            hipFuncAttributeMaxDynamicSharedMemorySize, 65536);
        int nwg = (int)((M / 256) * (N / 256));
        gemm_kernel<<<dim3(nwg), dim3(512), 65536, stream>>>(xd, wd, bias, out,
                                                             (int)M, (int)N, (int)K);
    }
}

// Round 7
// 545.434 us; speedup vs baseline: 1.9049x; 1.9049x over previous
//
#include <hip/hip_runtime.h>
#include <hip/hip_bf16.h>
#include <stdint.h>

// ---------- types ----------
typedef __attribute__((ext_vector_type(4))) float  f32x4;
typedef __attribute__((ext_vector_type(8))) short  bf16x8;
typedef __attribute__((ext_vector_type(8))) unsigned short u16x8;

#define MFMA16(d, x, y) d = __builtin_amdgcn_mfma_f32_16x16x32_bf16(x, y, d, 0, 0, 0)

// round f32 -> bf16 bits (RNE)
static __device__ inline unsigned short f2bf(float f) {
    union { float f; unsigned u; } a; a.f = f;
    unsigned u = a.u;
    unsigned lsb = (u >> 16) & 1u;
    u += 0x7fffu + lsb;
    return (unsigned short)(u >> 16);
}

// Emulate reference fp8_e4m3_round for positive x (x >= 1e-12).
static __device__ inline float fp8_e4m3_round(float x) {
    union { float f; unsigned u; } a; a.f = x;
    int e = (int)((a.u >> 23) & 255u) - 127;   // floor(log2(x)) exactly
    e = e < -6 ? -6 : (e > 8 ? 8 : e);
    union { unsigned u; float f; } stp, inv;
    stp.u = (unsigned)(e - 3 + 127) << 23;     // 2^(e-3)
    inv.u = (unsigned)(3 - e + 127) << 23;     // 2^(3-e)
    float r = rintf(x * inv.f) * stp.f;        // round-half-even == jnp.round
    return fminf(r, 448.0f);
}

// fp4 e2m1 level by strict midpoint comparison
static __device__ inline float fp4_level(float a) {
    return a > 2.5f ? (a > 3.5f ? (a > 5.0f ? 6.0f : 4.0f) : 3.0f)
                    : (a > 1.25f ? (a > 1.75f ? 2.0f : 1.5f)
                                 : (a > 0.75f ? 1.0f : (a > 0.25f ? 0.5f : 0.0f)));
}

// ---------- kernel 1: quantize+dequantize activations to bf16 ----------
__global__ void quant_x_kernel(const float* __restrict__ x, unsigned short* __restrict__ xd, int nblk) {
    int i = blockIdx.x * blockDim.x + threadIdx.x;
    if (i >= nblk) return;
    const float4* p = (const float4*)(x + (size_t)i * 16);
    float4 v0 = p[0], v1 = p[1], v2 = p[2], v3 = p[3];
    float vals[16] = { v0.x,v0.y,v0.z,v0.w, v1.x,v1.y,v1.z,v1.w,
                       v2.x,v2.y,v2.z,v2.w, v3.x,v3.y,v3.z,v3.w };
    float amax = 0.0f;
#pragma unroll
    for (int j = 0; j < 16; ++j) amax = fmaxf(amax, fabsf(vals[j]));
    float s0 = fmaxf(amax / 6.0f, 1e-12f);
    float s  = fmaxf(fp8_e4m3_round(s0), 1.0f / 512.0f);  // FP8_MIN = 2^-9
    u16x8 o0, o1;
#pragma unroll
    for (int j = 0; j < 16; ++j) {
        float v = vals[j] / s;
        float lev = fp4_level(fabsf(v));
        float q = copysignf(lev, v);
        unsigned short b = f2bf(q * s);
        if (j < 8) o0[j] = b; else o1[j - 8] = b;
    }
    u16x8* dst = (u16x8*)(xd + (size_t)i * 16);
    dst[0] = o0; dst[1] = o1;
}

// ---------- kernel 2: dequantize weights to bf16 ----------
__global__ void deq_w_kernel(const float* __restrict__ wq, const float* __restrict__ wsc,
                             unsigned short* __restrict__ wd, int nblk) {
    int i = blockIdx.x * blockDim.x + threadIdx.x;
    if (i >= nblk) return;
    float s = wsc[i];
    const float4* p = (const float4*)(wq + (size_t)i * 16);
    float4 v0 = p[0], v1 = p[1], v2 = p[2], v3 = p[3];
    float vals[16] = { v0.x,v0.y,v0.z,v0.w, v1.x,v1.y,v1.z,v1.w,
                       v2.x,v2.y,v2.z,v2.w, v3.x,v3.y,v3.z,v3.w };
    u16x8 o0, o1;
#pragma unroll
    for (int j = 0; j < 16; ++j) {
        unsigned short b = f2bf(vals[j] * s);
        if (j < 8) o0[j] = b; else o1[j - 8] = b;
    }
    u16x8* dst = (u16x8*)(wd + (size_t)i * 16);
    dst[0] = o0; dst[1] = o1;
}

// ---------- kernel 3: 256x256x64 bf16 GEMM, 2 barriers/K-tile, overlap ------
// C[M][N] = A[M][K] * B[N][K]^T + bias.  8 waves (2Mx4N), per-wave 128x64.
// LDS (128KB): A dbuf at 0/32768 (each: k0 slice @+0, k1 @+16384, st_16x32
// swizzled 1024B subtiles); B same at 65536.
// Phase (one per k-slice, ONE barrier each):
//   [vmcnt(4); bar; setprio1; 12 ds_reads (NEXT slice) -> regs;
//    2 stage_half (future tiles); 32 MFMA (CURRENT slice, regs read last
//    phase); setprio0]
// MFMA waits are compiler-COUNTED lgkm (in-order DS: wait lgkmcnt(12) =
// "my 12 new reads outstanding, old done") -> LDS pipe serves next-slice
// reads DURING the MFMA window instead of alternating with it.
// Ledger: stage k1[t+1]@H1(t)->buf b^1; k0[t+2]@H2(t)->buf b.
//   RAW: every read is 1 phase after its stage; gate vmcnt(4) at phase start
//        drains the 2-groups-old stage (4 newest kept = last phase's stage),
//        gate+barrier precede the reads for ALL waves.
//   WAR: region overwritten @H1(t) (k1 of b^1) was last read mid-H1(t-1);
//        those reads lgkm-drain before H2(t-1)'s MFMA, >=1 barrier before
//        the stage.  Same argument for H2's k0-of-b (read mid-H2(t-1)).
// No compiler-tracked vmem in the loop (only gload_lds) -> our asm vmcnt
// doesn't fight the compiler's waitcnt pass (round-6 lesson).
static __device__ __forceinline__ void stage_half(const unsigned short* g0, const unsigned short* g1,
                                                  size_t koff, char* d0) {
    __builtin_amdgcn_global_load_lds((const __attribute__((address_space(1))) void*)(g0 + koff),
                                     (__attribute__((address_space(3))) void*)d0, 16, 0, 0);
    __builtin_amdgcn_global_load_lds((const __attribute__((address_space(1))) void*)(g1 + koff),
                                     (__attribute__((address_space(3))) void*)(d0 + 1024), 16, 0, 0);
}

#define MFMA_ALL(AV, BV) {                                              \
    _Pragma("unroll")                                                   \
    for (int mf = 0; mf < 8; ++mf) {                                    \
        _Pragma("unroll")                                               \
        for (int nf = 0; nf < 4; ++nf) MFMA16(acc[mf][nf], AV[mf], BV[nf]); } }

#define READ12(AV, BV, OFF) {                                           \
    const char* _pa = lds + (OFF) + wr * 8192 + lane_off;               \
    const char* _pb = lds + 65536 + (OFF) + wc * 4096 + lane_off;       \
    _Pragma("unroll")                                                   \
    for (int i = 0; i < 8; ++i) AV[i] = *(const bf16x8*)(_pa + i * 1024); \
    _Pragma("unroll")                                                   \
    for (int i = 0; i < 4; ++i) BV[i] = *(const bf16x8*)(_pb + i * 1024); }

// H1(t): MFMA k0[t] (a1,b1); read k1[t] -> a2,b2; stage k1[t+1] -> buf b^1
#define PH1(T, B) {                                                     \
    asm volatile("s_waitcnt vmcnt(4)" ::: "memory");                    \
    __builtin_amdgcn_s_barrier();                                       \
    __builtin_amdgcn_s_setprio(1);                                      \
    READ12(a2, b2, (B) * 32768 + 16384);                                \
    stage_half(gA0, gA1, (size_t)((T) + 1) * 64 + 32, ldsA_w + (1 - (B)) * 32768 + 16384); \
    stage_half(gB0, gB1, (size_t)((T) + 1) * 64 + 32, ldsB_w + (1 - (B)) * 32768 + 16384); \
    MFMA_ALL(a1, b1);                                                   \
    __builtin_amdgcn_s_setprio(0); }

// H2(t): MFMA k1[t] (a2,b2); read k0[t+1] -> a1,b1; stage k0[t+2] -> buf b
#define PH2(T, B) {                                                     \
    asm volatile("s_waitcnt vmcnt(4)" ::: "memory");                    \
    __builtin_amdgcn_s_barrier();                                       \
    __builtin_amdgcn_s_setprio(1);                                      \
    READ12(a1, b1, (1 - (B)) * 32768);                                  \
    stage_half(gA0, gA1, (size_t)((T) + 2) * 64, ldsA_w + (B) * 32768); \
    stage_half(gB0, gB1, (size_t)((T) + 2) * 64, ldsB_w + (B) * 32768); \
    MFMA_ALL(a2, b2);                                                   \
    __builtin_amdgcn_s_setprio(0); }

__global__ __launch_bounds__(512, 2)
void gemm_kernel(const unsigned short* __restrict__ A, const unsigned short* __restrict__ Bw,
                 const float* __restrict__ bias, float* __restrict__ C,
                 int M, int N, int K) {
    extern __shared__ char lds[];
    const int tid  = threadIdx.x;
    const int lane = tid & 63;
    const int wid  = tid >> 6;
    const int wr   = wid >> 2;       // 0..1
    const int wc   = wid & 3;        // 0..3

    const int NXB = N >> 8, NYB = M >> 8;
    int bid = blockIdx.x;
    int bx, by;
    if (NXB == 64 && NYB == 16) {    // XCD-aware swizzle (8 XCDs, 1024 wgs)
        int xcd = bid & 7, c = bid >> 3;
        bx = xcd * 8 + (c & 7);
        by = c >> 3;
    } else { bx = bid % NXB; by = bid / NXB; }

    const int NT = K >> 6;           // K-tiles of 64 (K=4096 -> 64, even)

    // read-side swizzled lane offset within a 1024B subtile (st_16x32, 1 bit)
    int w0 = (lane & 15) * 64 + ((lane >> 4) << 4);
    const int lane_off = w0 ^ (((w0 >> 9) & 1) << 5);
    // write-side inverse permutation for staging: lane -> (row, col)
    const int u   = (lane * 16) ^ (lane & 32);
    const int r_l = u >> 6;
    const int c_l = (u & 63) >> 1;

    const unsigned short* gA0 = A  + (size_t)(by * 256 + wid * 32 + r_l) * K + c_l;
    const unsigned short* gA1 = gA0 + (size_t)16 * K;
    const unsigned short* gB0 = Bw + (size_t)(bx * 256 + wid * 32 + r_l) * K + c_l;
    const unsigned short* gB1 = gB0 + (size_t)16 * K;
    char* ldsA_w = lds + wid * 2048 + lane * 16;           // + buf*32768 + s*16384
    char* ldsB_w = lds + 65536 + wid * 2048 + lane * 16;

    f32x4 acc[8][4];
#pragma unroll
    for (int m = 0; m < 8; ++m)
#pragma unroll
        for (int n = 0; n < 4; ++n)
#pragma unroll
            for (int j = 0; j < 4; ++j) acc[m][n][j] = 0.0f;

    bf16x8 a1[8], a2[8], b1[4], b2[4];

    // ---- prologue: stage t0k0, t0k1, t1k0 (12 loads); read t0k0 ----
    stage_half(gA0, gA1, 0,  ldsA_w);
    stage_half(gB0, gB1, 0,  ldsB_w);
    stage_half(gA0, gA1, 32, ldsA_w + 16384);
    stage_half(gB0, gB1, 32, ldsB_w + 16384);
    stage_half(gA0, gA1, 64, ldsA_w + 32768);
    stage_half(gB0, gB1, 64, ldsB_w + 32768);
    asm volatile("s_waitcnt vmcnt(8)" ::: "memory");   // t0k0 (A+B) landed
    __builtin_amdgcn_s_barrier();
    READ12(a1, b1, 0);

    // ---- main loop: tiles 0..NT-3, two K-tiles per iteration ----
    for (int t = 0; t <= NT - 4; t += 2) {
        PH1(t, 0);  PH2(t, 0);
        PH1(t + 1, 1);  PH2(t + 1, 1);
    }

    // ---- tile NT-2 (buf 0): normal H1; H2 without stage ----
    PH1(NT - 2, 0);
    {
        asm volatile("s_waitcnt vmcnt(4)" ::: "memory");   // drains k0[NT-1]
        __builtin_amdgcn_s_barrier();
        READ12(a1, b1, 32768);                             // k0[NT-1], buf 1
        MFMA_ALL(a2, b2);
    }
    // ---- tile NT-1 (buf 1): H1 with vmcnt(0); final MFMA, no barrier ----
    {
        asm volatile("s_waitcnt vmcnt(0)" ::: "memory");   // drains k1[NT-1]
        __builtin_amdgcn_s_barrier();
        READ12(a2, b2, 32768 + 16384);                     // k1[NT-1]
        MFMA_ALL(a1, b1);
        MFMA_ALL(a2, b2);
    }

    // ---- C write: col = lane&15, row = (lane>>4)*4 + j ----
    const int row0 = by * 256 + wr * 128;
    const int col0 = bx * 256 + wc * 64;
#pragma unroll
    for (int nf = 0; nf < 4; ++nf) {
        int col = col0 + nf * 16 + (lane & 15);
        float bv = bias[col];
#pragma unroll
        for (int mf = 0; mf < 8; ++mf) {
#pragma unroll
            for (int j = 0; j < 4; ++j) {
                int row = row0 + mf * 16 + ((lane >> 4) << 2) + j;
                C[(size_t)row * N + col] = acc[mf][nf][j] + bv;
            }
        }
    }
}

// ---------- host ----------
extern "C" void kernel_launch(void* const* d_in, const int* in_sizes, int n_in,
                              void* d_out, int out_size, void* d_ws, size_t ws_size,
                              hipStream_t stream) {
    const float* x    = (const float*)d_in[0];
    const float* wq   = (const float*)d_in[1];
    const float* wsc  = (const float*)d_in[2];
    const float* bias = (const float*)d_in[3];
    float* out = (float*)d_out;

    const long N = in_sizes[3];                 // 16384
    const long K = (long)in_sizes[1] / N;       // 4096
    const long M = (long)in_sizes[0] / K;       // 4096

    size_t need = ((size_t)(M * K) + (size_t)(N * K)) * sizeof(unsigned short);
    if (ws_size < need) return;

    unsigned short* xd = (unsigned short*)d_ws;          // [M][K] bf16
    unsigned short* wd = xd + (size_t)M * K;             // [N][K] bf16

    {
        int nblk = (int)(M * K / 16);
        quant_x_kernel<<<(nblk + 255) / 256, 256, 0, stream>>>(x, xd, nblk);
    }
    {
        int nblk = (int)(N * K / 16);
        deq_w_kernel<<<(nblk + 255) / 256, 256, 0, stream>>>(wq, wsc, wd, nblk);
    }
    {
        hipFuncSetAttribute((const void*)gemm_kernel,
                            hipFuncAttributeMaxDynamicSharedMemorySize, 131072);
        int nwg = (int)((M / 256) * (N / 256));
        gemm_kernel<<<dim3(nwg), dim3(512), 131072, stream>>>(xd, wd, bias, out,
                                                              (int)M, (int)N, (int)K);
    }
}